// Round 10
// baseline (226.850 us; speedup 1.0000x reference)
//
#include <hip/hip_runtime.h>
#include <hip/hip_bf16.h>

typedef unsigned int u32;
typedef unsigned short u16;
using bf16x8 = __attribute__((ext_vector_type(8))) short;
using f32x4  = __attribute__((ext_vector_type(4))) float;

#define S_LEN 2048
#define DK 64
#define NH 16
#define DMODEL 1024
#define NROWS 4096   // B * S

// ---------- helpers ----------
__device__ __forceinline__ u16 f2bf(float f){
  u32 u = __builtin_bit_cast(u32, f);
  u += 0x7fffu + ((u >> 16) & 1u);   // round-to-nearest-even
  return (u16)(u >> 16);
}

__device__ __forceinline__ void gload_lds16(const u16* g, u16* l){
  // async global->LDS, 16B per lane; LDS dest = wave-uniform base + lane*16
  __builtin_amdgcn_global_load_lds(
      (__attribute__((address_space(1))) u32*)(void*)const_cast<u16*>(g),
      (__attribute__((address_space(3))) u32*)(void*)l, 16, 0, 0);
}

// counted-vmcnt barrier: 2 staging loads (oldest) guaranteed done,
// 4 attn stores may remain in flight across the barrier.
#define TILE_BARRIER_VM4() do { \
  asm volatile("s_waitcnt vmcnt(4) lgkmcnt(0)" ::: "memory"); \
  __builtin_amdgcn_s_barrier(); \
  __builtin_amdgcn_sched_barrier(0); \
} while (0)

#define TILE_BARRIER_VM0() do { \
  asm volatile("s_waitcnt vmcnt(0) lgkmcnt(0)" ::: "memory"); \
  __builtin_amdgcn_s_barrier(); \
  __builtin_amdgcn_sched_barrier(0); \
} while (0)

// ---------- f32 -> bf16 conversion, weights only (4 x 1M elems) ----------
__global__ void cvt_w(const float* __restrict__ wq, const float* __restrict__ wk,
                      const float* __restrict__ wv, const float* __restrict__ wo,
                      u16* __restrict__ dstbase)
{
  const int y = blockIdx.y;
  const float* src = (y==0)?wq:(y==1)?wk:(y==2)?wv:wo;
  u16* dst = dstbase + (size_t)y * (DMODEL*DMODEL);
  const int i = blockIdx.x * blockDim.x + threadIdx.x;   // 1024*256 = 262144 = n4
  float4 val = reinterpret_cast<const float4*>(src)[i];
  ushort4 o;
  o.x = f2bf(val.x); o.y = f2bf(val.y); o.z = f2bf(val.z); o.w = f2bf(val.w);
  reinterpret_cast<ushort4*>(dst)[i] = o;
}

// ---------- QKV GEMM: A = f32 inputs (reg-staged + converted), B = bf16 weights ----------
// z=0 (q_in,Wq)->Qh (scaled log2e/8), z=1 (k_in,Wk)->Kh, z=2 (v_in,Wv)->Vt^T
__global__ __launch_bounds__(256)
void gemm_qkv(const float* __restrict__ qin, const float* __restrict__ kin,
              const float* __restrict__ vin, const u16* __restrict__ Wbase,
              u16* __restrict__ Qh, u16* __restrict__ Kh, u16* __restrict__ Vt)
{
  __shared__ u16 smem[32768];          // 64 KiB: As [2][8192] | Bs [2][8192]
  u16* As = smem;
  u16* Bs = smem + 16384;

  const int tid  = threadIdx.x;
  const int lane = tid & 63;
  const int wid  = tid >> 6;            // 4 waves
  const int lo = lane & 15, hi = lane >> 4;
  const int z = blockIdx.z;
  const int m0 = blockIdx.x * 128;
  const int n0 = blockIdx.y * 128;
  const float* ga = ((z==0)?qin:(z==1)?kin:vin) + (size_t)m0 * DMODEL;
  const u16*   gb = Wbase + (size_t)z * (DMODEL*DMODEL) + (size_t)n0 * DMODEL;

  const int wm = (wid >> 1) * 64;
  const int wn = (wid & 1) * 64;

  f32x4 acc[4][4] = {};

  // A: reg-stage f32 -> bf16 -> LDS (numerically identical to pre-cvt path)
  auto stageA = [&](int buf, int kt){
    const float* a = ga + kt * 64;
    #pragma unroll
    for (int i = 0; i < 4; ++i){
      const int chunk = i*256 + tid;    // 1024 chunks (128 rows x 8)
      const int row = chunk >> 3, c8 = chunk & 7;
      const float* src = a + (size_t)row*DMODEL + c8*8;
      const float4 v0 = *reinterpret_cast<const float4*>(src);
      const float4 v1 = *reinterpret_cast<const float4*>(src + 4);
      union { bf16x8 v; __hip_bfloat162 h[4]; } u_;
      u_.h[0] = __float22bfloat162_rn(float2{v0.x, v0.y});
      u_.h[1] = __float22bfloat162_rn(float2{v0.z, v0.w});
      u_.h[2] = __float22bfloat162_rn(float2{v1.x, v1.y});
      u_.h[3] = __float22bfloat162_rn(float2{v1.z, v1.w});
      *reinterpret_cast<bf16x8*>(&As[buf*8192 + chunk*8]) = u_.v;
    }
  };
  // B: async global->LDS
  auto stageB = [&](int buf, int kt){
    const u16* b = gb + kt * 64;
    #pragma unroll
    for (int i = 0; i < 4; ++i){
      const int chunk = i*256 + tid;
      const int row = chunk >> 3, c8 = chunk & 7;
      gload_lds16(b + (size_t)row*DMODEL + c8*8, &Bs[buf*8192 + (i*256 + wid*64)*8]);
    }
  };

  stageB(0, 0);
  stageA(0, 0);
  __syncthreads();

  for (int t = 0; t < DMODEL/64; ++t){
    const int buf = t & 1;
    if (t + 1 < DMODEL/64){ stageB(buf ^ 1, t + 1); stageA(buf ^ 1, t + 1); }
    const u16* as = &As[buf*8192];
    const u16* bs = &Bs[buf*8192];
    #pragma unroll
    for (int ks = 0; ks < 2; ++ks){
      bf16x8 af[4], bfr[4];
      #pragma unroll
      for (int i = 0; i < 4; ++i){
        af[i]  = *reinterpret_cast<const bf16x8*>(&as[(wm + i*16 + lo)*64 + ks*32 + hi*8]);
        bfr[i] = *reinterpret_cast<const bf16x8*>(&bs[(wn + i*16 + lo)*64 + ks*32 + hi*8]);
      }
      #pragma unroll
      for (int mi = 0; mi < 4; ++mi)
        #pragma unroll
        for (int ni = 0; ni < 4; ++ni)
          acc[mi][ni] = __builtin_amdgcn_mfma_f32_16x16x32_bf16(af[mi], bfr[ni], acc[mi][ni], 0, 0, 0);
    }
    __syncthreads();
  }

  // LDS transpose epilogue; row pitch 136 keeps 16B alignment, banks spread
  const float scale = (z == 0) ? 0.18033688011112043f : 1.0f;  // log2(e)/8
  if (z == 2){
    #pragma unroll
    for (int mi = 0; mi < 4; ++mi)
    #pragma unroll
    for (int ni = 0; ni < 4; ++ni)
    #pragma unroll
    for (int r = 0; r < 4; ++r)
      smem[(size_t)(wn + ni*16 + lo)*136 + wm + mi*16 + hi*4 + r] = f2bf(acc[mi][ni][r]);
  } else {
    #pragma unroll
    for (int mi = 0; mi < 4; ++mi)
    #pragma unroll
    for (int ni = 0; ni < 4; ++ni)
    #pragma unroll
    for (int r = 0; r < 4; ++r)
      smem[(size_t)(wm + mi*16 + hi*4 + r)*136 + wn + ni*16 + lo] = f2bf(acc[mi][ni][r] * scale);
  }
  __syncthreads();
  const int b = m0 >> 11, s0 = m0 & 2047;
  #pragma unroll
  for (int it = 0; it < 8; ++it){
    const int c = it*256 + tid;       // 2048 chunks of 8 elements
    const int rr = c >> 4, cc = c & 15;
    bf16x8 v = *reinterpret_cast<const bf16x8*>(&smem[(size_t)rr*136 + cc*8]);
    if (z == 2){
      const int gn = n0 + rr, h = gn >> 6, d = gn & 63;
      *reinterpret_cast<bf16x8*>(&Vt[(((size_t)(b*NH + h))*DK + d)*S_LEN + s0 + cc*8]) = v;
    } else {
      const int gn = n0 + cc*8, h = gn >> 6, d0 = gn & 63;
      u16* dst = z ? Kh : Qh;
      *reinterpret_cast<bf16x8*>(&dst[(((size_t)(b*NH + h))*S_LEN + s0 + rr)*DK + d0]) = v;
    }
  }
}

// ---------- out GEMM: A = Ctx bf16, B = Wo bf16, f32 out + bias, nt stores ----------
__global__ __launch_bounds__(256)
void gemm_out(const u16* __restrict__ Abase, const u16* __restrict__ Bbase,
              float* __restrict__ Out, const float* __restrict__ bias)
{
  __shared__ u16 smem[32768];
  u16* As = smem;
  u16* Bs = smem + 16384;

  const int tid  = threadIdx.x;
  const int lane = tid & 63;
  const int wid  = tid >> 6;
  const int lo = lane & 15, hi = lane >> 4;
  const int m0 = blockIdx.x * 128;
  const int n0 = blockIdx.y * 128;
  const u16* ga = Abase + (size_t)m0 * DMODEL;
  const u16* gb = Bbase + (size_t)n0 * DMODEL;

  const int wm = (wid >> 1) * 64;
  const int wn = (wid & 1) * 64;

  f32x4 acc[4][4] = {};

  auto stage = [&](int buf, int kt){
    const u16* a = ga + kt * 64;
    const u16* b = gb + kt * 64;
    #pragma unroll
    for (int i = 0; i < 4; ++i){
      const int chunk = i*256 + tid;
      const int row = chunk >> 3, c8 = chunk & 7;
      gload_lds16(a + (size_t)row*DMODEL + c8*8, &As[buf*8192 + (i*256 + wid*64)*8]);
      gload_lds16(b + (size_t)row*DMODEL + c8*8, &Bs[buf*8192 + (i*256 + wid*64)*8]);
    }
  };

  stage(0, 0);
  __syncthreads();

  for (int t = 0; t < DMODEL/64; ++t){
    const int buf = t & 1;
    if (t + 1 < DMODEL/64) stage(buf ^ 1, t + 1);
    const u16* as = &As[buf*8192];
    const u16* bs = &Bs[buf*8192];
    #pragma unroll
    for (int ks = 0; ks < 2; ++ks){
      bf16x8 af[4], bfr[4];
      #pragma unroll
      for (int i = 0; i < 4; ++i){
        af[i]  = *reinterpret_cast<const bf16x8*>(&as[(wm + i*16 + lo)*64 + ks*32 + hi*8]);
        bfr[i] = *reinterpret_cast<const bf16x8*>(&bs[(wn + i*16 + lo)*64 + ks*32 + hi*8]);
      }
      #pragma unroll
      for (int mi = 0; mi < 4; ++mi)
        #pragma unroll
        for (int ni = 0; ni < 4; ++ni)
          acc[mi][ni] = __builtin_amdgcn_mfma_f32_16x16x32_bf16(af[mi], bfr[ni], acc[mi][ni], 0, 0, 0);
    }
    __syncthreads();
  }

  #pragma unroll
  for (int mi = 0; mi < 4; ++mi)
  #pragma unroll
  for (int ni = 0; ni < 4; ++ni)
  #pragma unroll
  for (int r = 0; r < 4; ++r){
    const int m = m0 + wm + mi*16 + hi*4 + r;
    const int n = n0 + wn + ni*16 + lo;
    __builtin_nontemporal_store(acc[mi][ni][r] + bias[n],
                                &Out[(size_t)m * DMODEL + n]);
  }
}

// ---------- fused attention (unchanged from round 9) ----------
__global__ __launch_bounds__(512)
void attn_fused(const u16* __restrict__ Qh, const u16* __restrict__ Kh,
                const u16* __restrict__ Vt, float* __restrict__ attn,
                u16* __restrict__ ctx)
{
  constexpr int S = S_LEN;
  __shared__ u16 KV[2][2][64*64];    // 32 KiB: pass2 [buf][K|V]; pass1 [buf] = 128-row K
  __shared__ float Pf[8][16*40];     // 20 KiB, per-wave P half-tile (16q x 32k)

  const int tid = threadIdx.x, lane = tid & 63, w = tid >> 6;   // 8 waves
  const int lo = lane & 15, hi = lane >> 4;

  const int idx = blockIdx.x;
  const int slot = idx >> 3;
  const int qt = slot & 15;
  const int bh = (idx & 7) + 8 * (slot >> 4);

  const int q0 = qt*128 + w*16;
  const u16* Qb = Qh + (size_t)bh * S * DK;
  const u16* Kb = Kh + (size_t)bh * S * DK;
  const u16* Vb = Vt + (size_t)bh * DK * S;
  float* attn_b = attn + (size_t)bh * S * S;

  bf16x8 aq[2];
  #pragma unroll
  for (int ks = 0; ks < 2; ++ks)
    aq[ks] = *reinterpret_cast<const bf16x8*>(
        &Qb[(size_t)(q0 + lo) * DK + ks*32 + hi*8]);

  auto qk = [&](const u16* tile, f32x4 (&s)[4]){
    #pragma unroll
    for (int ks = 0; ks < 2; ++ks){
      bf16x8 bk[4];
      #pragma unroll
      for (int kf = 0; kf < 4; ++kf){
        const int row = kf*16 + lo;
        bk[kf] = *reinterpret_cast<const bf16x8*>(
            &tile[row*64 + (((ks*4 + hi) ^ (row&7))*8)]);
      }
      #pragma unroll
      for (int kf = 0; kf < 4; ++kf)
        s[kf] = __builtin_amdgcn_mfma_f32_16x16x32_bf16(aq[ks], bk[kf], s[kf], 0, 0, 0);
    }
  };

  // ---- pass 1: 128-row K tiles (LDS aliased over pass2's K+V), 16 barriers ----
  u16* KP0 = &KV[0][0][0];
  u16* KP1 = &KV[1][0][0];
  auto stage128 = [&](u16* dst, int t16){
    const u16* kt = Kb + (size_t)t16 * 128 * DK;
    #pragma unroll
    for (int i = 0; i < 2; ++i){
      const int u_ = i*512 + tid;
      const int r = u_ >> 3, c = u_ & 7;
      gload_lds16(kt + (size_t)r*DK + ((c ^ (r&7))*8), dst + (i*512 + w*64)*8);
    }
  };
  stage128(KP0, 0);
  __syncthreads();
  float l_part[4] = {};
  for (int t = 0; t < S/128; ++t){
    u16* cur = (t & 1) ? KP1 : KP0;
    u16* nxt = (t & 1) ? KP0 : KP1;
    if (t + 1 < S/128) stage128(nxt, t + 1);
    #pragma unroll
    for (int sub = 0; sub < 2; ++sub){
      f32x4 s[4] = {};
      qk(cur + sub*4096, s);
      #pragma unroll
      for (int r = 0; r < 4; ++r)
        l_part[r] += exp2f(s[0][r]) + exp2f(s[1][r]) + exp2f(s[2][r]) + exp2f(s[3][r]);
    }
    __syncthreads();
  }
  float inv_l[4];
  #pragma unroll
  for (int r = 0; r < 4; ++r){
    float v = l_part[r];
    v += __shfl_xor(v, 1, 64);
    v += __shfl_xor(v, 2, 64);
    v += __shfl_xor(v, 4, 64);
    v += __shfl_xor(v, 8, 64);
    inv_l[r] = 1.0f / v;
  }

  // ---- pass 2: K+V 64-row tiles, nt stores ----
  const int sr = tid >> 3, sc = tid & 7;
  auto stageK = [&](int buf, int t){
    gload_lds16(Kb + (size_t)t*64*DK + (size_t)sr*DK + ((sc ^ (sr&7))*8),
                &KV[buf][0][w*512]);
  };
  auto stageV = [&](int buf, int t){
    gload_lds16(Vb + (size_t)sr*S + t*64 + ((sc ^ (sr&7))*8),
                &KV[buf][1][w*512]);
  };

  stageK(0, 0); stageV(0, 0);
  TILE_BARRIER_VM0();
  f32x4 o[4] = {};
  for (int t = 0; t < S/64; ++t){
    const int buf = t & 1;
    if (t + 1 < S/64){ stageK(buf ^ 1, t + 1); stageV(buf ^ 1, t + 1); }
    f32x4 s[4] = {};
    qk(&KV[buf][0][0], s);

    #pragma unroll
    for (int half = 0; half < 2; ++half){
      #pragma unroll
      for (int k2 = 0; k2 < 2; ++k2){
        const int kf = half*2 + k2;
        #pragma unroll
        for (int r = 0; r < 4; ++r){
          const int row = hi*4 + r;
          const int col = k2*16 + lo;
          Pf[w][row*40 + ((((col>>2) ^ (row&7)) << 2) | (col & 3))] =
              exp2f(s[kf][r]) * inv_l[r];
        }
      }
      #pragma unroll
      for (int j = 0; j < 2; ++j){
        const int row = j*8 + (lane >> 3);
        const int cb  = (lane & 7) * 4;
        f32x4 vv = *reinterpret_cast<const f32x4*>(
            &Pf[w][row*40 + ((((cb>>2) ^ (row&7)) << 2))]);
        __builtin_nontemporal_store(vv, reinterpret_cast<f32x4*>(
            &attn_b[(size_t)(q0 + row)*S + t*64 + half*32 + cb]));
      }
      {
        const int row = lo;
        const f32x4 pa = *reinterpret_cast<const f32x4*>(
            &Pf[w][row*40 + (((2*hi) ^ (row&7)) << 2)]);
        const f32x4 pb = *reinterpret_cast<const f32x4*>(
            &Pf[w][row*40 + (((2*hi + 1) ^ (row&7)) << 2)]);
        union { bf16x8 v; __hip_bfloat162 h[4]; } u_;
        u_.h[0] = __float22bfloat162_rn(float2{pa[0], pa[1]});
        u_.h[1] = __float22bfloat162_rn(float2{pa[2], pa[3]});
        u_.h[2] = __float22bfloat162_rn(float2{pb[0], pb[1]});
        u_.h[3] = __float22bfloat162_rn(float2{pb[2], pb[3]});
        bf16x8 bv[4];
        #pragma unroll
        for (int df = 0; df < 4; ++df){
          const int vrow = df*16 + lo;
          bv[df] = *reinterpret_cast<const bf16x8*>(
              &KV[buf][1][vrow*64 + (((half*4 + hi) ^ (vrow&7))*8)]);
        }
        #pragma unroll
        for (int df = 0; df < 4; ++df)
          o[df] = __builtin_amdgcn_mfma_f32_16x16x32_bf16(u_.v, bv[df], o[df], 0, 0, 0);
      }
    }

    if (t + 1 < S/64){
      TILE_BARRIER_VM4();
    }
  }

  // ctx epilogue: [b][s][h*64 + d] bf16
  const int b = bh >> 4, h = bh & 15;
  #pragma unroll
  for (int df = 0; df < 4; ++df)
  #pragma unroll
  for (int r = 0; r < 4; ++r){
    const int qq = q0 + hi*4 + r;
    const int d  = df*16 + lo;
    ctx[((size_t)b * S + qq) * DMODEL + h*DK + d] = f2bf(o[df][r]);
  }
}

// ---------- launch ----------
extern "C" void kernel_launch(void* const* d_in, const int* in_sizes, int n_in,
                              void* d_out, int out_size, void* d_ws, size_t ws_size,
                              hipStream_t stream)
{
  const float* q_in = (const float*)d_in[0];
  const float* k_in = (const float*)d_in[1];
  const float* v_in = (const float*)d_in[2];
  const float* wq   = (const float*)d_in[3];
  const float* wk   = (const float*)d_in[4];
  const float* wv   = (const float*)d_in[5];
  const float* wo   = (const float*)d_in[6];
  const float* bo   = (const float*)d_in[7];

  u16* ws = (u16*)d_ws;
  u16* W  = ws;                                          // Wq,Wk,Wv,Wo bf16 contiguous
  u16* Qh = W  + (size_t)4*DMODEL*DMODEL;
  u16* Kh = Qh + (size_t)NROWS*DMODEL;
  u16* Vt = Kh + (size_t)NROWS*DMODEL;
  u16* Ctx= Vt + (size_t)NROWS*DMODEL;

  cvt_w<<<dim3(1024, 4), 256, 0, stream>>>(wq, wk, wv, wo, W);

  gemm_qkv<<<dim3(32, 8, 3), 256, 0, stream>>>(q_in, k_in, v_in, W, Qh, Kh, Vt);

  float* out0 = (float*)d_out;
  float* attn = out0 + (size_t)NROWS * DMODEL;
  attn_fused<<<dim3(512), 512, 0, stream>>>(Qh, Kh, Vt, attn, Ctx);

  gemm_out<<<dim3(32, 8), 256, 0, stream>>>(Ctx, W + (size_t)3*DMODEL*DMODEL, out0, bo);
}

// Round 11
// 221.618 us; speedup vs baseline: 1.0236x; 1.0236x over previous
//
#include <hip/hip_runtime.h>
#include <hip/hip_bf16.h>

typedef unsigned int u32;
typedef unsigned short u16;
using bf16x8 = __attribute__((ext_vector_type(8))) short;
using f32x4  = __attribute__((ext_vector_type(4))) float;

#define S_LEN 2048
#define DK 64
#define NH 16
#define DMODEL 1024
#define NROWS 4096   // B * S

// ---------- helpers ----------
__device__ __forceinline__ u16 f2bf(float f){
  u32 u = __builtin_bit_cast(u32, f);
  u += 0x7fffu + ((u >> 16) & 1u);   // round-to-nearest-even
  return (u16)(u >> 16);
}

__device__ __forceinline__ void gload_lds16(const u16* g, u16* l){
  // async global->LDS, 16B per lane; LDS dest = wave-uniform base + lane*16
  __builtin_amdgcn_global_load_lds(
      (__attribute__((address_space(1))) u32*)(void*)const_cast<u16*>(g),
      (__attribute__((address_space(3))) u32*)(void*)l, 16, 0, 0);
}

// counted-vmcnt barriers
#define BARRIER_VM(N) do { \
  asm volatile("s_waitcnt vmcnt(" #N ") lgkmcnt(0)" ::: "memory"); \
  __builtin_amdgcn_s_barrier(); \
  __builtin_amdgcn_sched_barrier(0); \
} while (0)

// ---------- f32 -> bf16 conversion, all 7 tensors in one launch ----------
__global__ void cvt_all(const float* __restrict__ q, const float* __restrict__ k,
                        const float* __restrict__ v, const float* __restrict__ wq,
                        const float* __restrict__ wk, const float* __restrict__ wv,
                        const float* __restrict__ wo, u16* __restrict__ ws)
{
  const int y = blockIdx.y;
  const int n4 = (y < 3) ? (NROWS*DMODEL/4) : (DMODEL*DMODEL/4);
  const int i = blockIdx.x * blockDim.x + threadIdx.x;
  if (i >= n4) return;
  const float* src = (y==0)?q:(y==1)?k:(y==2)?v:(y==3)?wq:(y==4)?wk:(y==5)?wv:wo;
  u16* dst = ws + ((y < 3) ? (size_t)y*(NROWS*DMODEL)
                           : (size_t)3*(NROWS*DMODEL) + (size_t)(y-3)*(DMODEL*DMODEL));
  float4 val = reinterpret_cast<const float4*>(src)[i];
  ushort4 o;
  o.x = f2bf(val.x); o.y = f2bf(val.y); o.z = f2bf(val.z); o.w = f2bf(val.w);
  reinterpret_cast<ushort4*>(dst)[i] = o;
}

// ---------- GEMM core (m97 structure): C[m,n] = sum_k A[m,k]*Bt[n,k], K=1024 ----------
template<bool OUTGEMM>
__global__ __launch_bounds__(256)
void gemm_mha(const u16* __restrict__ Abase, const u16* __restrict__ Bbase,
              u16* __restrict__ Qh, u16* __restrict__ Kh, u16* __restrict__ Vt,
              float* __restrict__ Out, const float* __restrict__ bias)
{
  __shared__ u16 smem[32768];          // 64 KiB: As [2][8192] | Bs [2][8192]
  u16* As = smem;
  u16* Bs = smem + 16384;

  const int tid  = threadIdx.x;
  const int lane = tid & 63;
  const int wid  = tid >> 6;            // 4 waves
  const int lo = lane & 15, hi = lane >> 4;
  const int z = OUTGEMM ? 0 : blockIdx.z;
  const int m0 = blockIdx.x * 128;
  const int n0 = blockIdx.y * 128;
  const u16* ga = Abase + (size_t)z * (NROWS*DMODEL)  + (size_t)m0 * DMODEL;
  const u16* gb = Bbase + (size_t)z * (DMODEL*DMODEL) + (size_t)n0 * DMODEL;

  const int wm = (wid >> 1) * 64;
  const int wn = (wid & 1) * 64;

  f32x4 acc[4][4] = {};

  auto stage = [&](int buf, int kt){
    const u16* a = ga + kt * 64;
    const u16* b = gb + kt * 64;
    #pragma unroll
    for (int i = 0; i < 4; ++i){
      const int chunk = i*256 + tid;    // 1024 16B-chunks (128 rows x 8)
      const int row = chunk >> 3, c8 = chunk & 7;
      gload_lds16(a + (size_t)row*DMODEL + c8*8, &As[buf*8192 + (i*256 + wid*64)*8]);
      gload_lds16(b + (size_t)row*DMODEL + c8*8, &Bs[buf*8192 + (i*256 + wid*64)*8]);
    }
  };

  stage(0, 0);
  __syncthreads();

  for (int t = 0; t < DMODEL/64; ++t){
    const int buf = t & 1;
    if (t + 1 < DMODEL/64) stage(buf ^ 1, t + 1);
    const u16* as = &As[buf*8192];
    const u16* bs = &Bs[buf*8192];
    #pragma unroll
    for (int ks = 0; ks < 2; ++ks){
      bf16x8 af[4], bfr[4];
      #pragma unroll
      for (int i = 0; i < 4; ++i){
        af[i]  = *reinterpret_cast<const bf16x8*>(&as[(wm + i*16 + lo)*64 + ks*32 + hi*8]);
        bfr[i] = *reinterpret_cast<const bf16x8*>(&bs[(wn + i*16 + lo)*64 + ks*32 + hi*8]);
      }
      #pragma unroll
      for (int mi = 0; mi < 4; ++mi)
        #pragma unroll
        for (int ni = 0; ni < 4; ++ni)
          acc[mi][ni] = __builtin_amdgcn_mfma_f32_16x16x32_bf16(af[mi], bfr[ni], acc[mi][ni], 0, 0, 0);
    }
    __syncthreads();
  }

  // C/D layout: col = lane&15 (lo), row = hi*4 + r
  if constexpr (OUTGEMM){
    #pragma unroll
    for (int mi = 0; mi < 4; ++mi)
    #pragma unroll
    for (int ni = 0; ni < 4; ++ni)
    #pragma unroll
    for (int r = 0; r < 4; ++r){
      const int m = m0 + wm + mi*16 + hi*4 + r;
      const int n = n0 + wn + ni*16 + lo;
      __builtin_nontemporal_store(acc[mi][ni][r] + bias[n],
                                  &Out[(size_t)m * DMODEL + n]);
    }
  } else {
    // LDS transpose epilogue; row pitch 136 keeps 16B alignment, banks spread
    const float scale = (z == 0) ? 0.18033688011112043f : 1.0f;  // log2(e)/8
    if (z == 2){
      #pragma unroll
      for (int mi = 0; mi < 4; ++mi)
      #pragma unroll
      for (int ni = 0; ni < 4; ++ni)
      #pragma unroll
      for (int r = 0; r < 4; ++r)
        smem[(size_t)(wn + ni*16 + lo)*136 + wm + mi*16 + hi*4 + r] = f2bf(acc[mi][ni][r]);
    } else {
      #pragma unroll
      for (int mi = 0; mi < 4; ++mi)
      #pragma unroll
      for (int ni = 0; ni < 4; ++ni)
      #pragma unroll
      for (int r = 0; r < 4; ++r)
        smem[(size_t)(wm + mi*16 + hi*4 + r)*136 + wn + ni*16 + lo] = f2bf(acc[mi][ni][r] * scale);
    }
    __syncthreads();
    const int b = m0 >> 11, s0 = m0 & 2047;
    #pragma unroll
    for (int it = 0; it < 8; ++it){
      const int c = it*256 + tid;       // 2048 chunks of 8 elements
      const int rr = c >> 4, cc = c & 15;
      bf16x8 v = *reinterpret_cast<const bf16x8*>(&smem[(size_t)rr*136 + cc*8]);
      if (z == 2){
        const int gn = n0 + rr, h = gn >> 6, d = gn & 63;
        *reinterpret_cast<bf16x8*>(&Vt[(((size_t)(b*NH + h))*DK + d)*S_LEN + s0 + cc*8]) = v;
      } else {
        const int gn = n0 + cc*8, h = gn >> 6, d0 = gn & 63;
        u16* dst = z ? Kh : Qh;
        *reinterpret_cast<bf16x8*>(&dst[(((size_t)(b*NH + h))*S_LEN + s0 + rr)*DK + d0]) = v;
      }
    }
  }
}

// ---------- fused attention ----------
// 512 blocks (XCD-swizzled), 512 threads = 8 waves x 16 q-rows.
// Pass 1: 128-row K tiles, TRIPLE-buffered with 2-deep prefetch + counted
// vmcnt(2) barriers -> staging latency never exposed.
// Pass 2: 64-row K+V double-buffered tiles, nontemporal coalesced attn stores,
// counted-vmcnt barriers keep stores in flight. ctx epilogue via LDS (16B/lane).
__global__ __launch_bounds__(512)
void attn_fused(const u16* __restrict__ Qh, const u16* __restrict__ Kh,
                const u16* __restrict__ Vt, float* __restrict__ attn,
                u16* __restrict__ ctx)
{
  constexpr int S = S_LEN;
  // 53248 B carved manually:
  //  pass 2: KV[buf][K|V] = SM + buf*8192 + {0,4096}; Pf = (float*)(SM+16384), 8x640 f32
  //  pass 1: 3 K-buffers of 8192 u16 at SM + (t%3)*8192 (spans KV + part of Pf)
  __shared__ u16 SM[26624];

  const int tid = threadIdx.x, lane = tid & 63, w = tid >> 6;   // 8 waves
  const int lo = lane & 15, hi = lane >> 4;
  float* Pf = (float*)(SM + 16384);

  // bijective XCD mapping: 16 q-tiles of one (b,h) share an XCD
  const int idx = blockIdx.x;
  const int slot = idx >> 3;
  const int qt = slot & 15;
  const int bh = (idx & 7) + 8 * (slot >> 4);

  const int q0 = qt*128 + w*16;      // this wave's 16 q rows
  const u16* Qb = Qh + (size_t)bh * S * DK;
  const u16* Kb = Kh + (size_t)bh * S * DK;
  const u16* Vb = Vt + (size_t)bh * DK * S;
  float* attn_b = attn + (size_t)bh * S * S;

  // Q fragments in registers for the whole kernel
  bf16x8 aq[2];
  #pragma unroll
  for (int ks = 0; ks < 2; ++ks)
    aq[ks] = *reinterpret_cast<const bf16x8*>(
        &Qb[(size_t)(q0 + lo) * DK + ks*32 + hi*8]);

  // qk on a 64x64 swizzled tile
  auto qk = [&](const u16* tile, f32x4 (&s)[4]){
    #pragma unroll
    for (int ks = 0; ks < 2; ++ks){
      bf16x8 bk[4];
      #pragma unroll
      for (int kf = 0; kf < 4; ++kf){
        const int row = kf*16 + lo;
        bk[kf] = *reinterpret_cast<const bf16x8*>(
            &tile[row*64 + (((ks*4 + hi) ^ (row&7))*8)]);
      }
      #pragma unroll
      for (int kf = 0; kf < 4; ++kf)
        s[kf] = __builtin_amdgcn_mfma_f32_16x16x32_bf16(aq[ks], bk[kf], s[kf], 0, 0, 0);
    }
  };

  // ---- pass 1: 128-row K tiles, triple-buffered, counted-vmcnt barriers ----
  auto stage128 = [&](u16* dst, int t16){
    const u16* kt = Kb + (size_t)t16 * 128 * DK;
    #pragma unroll
    for (int i = 0; i < 2; ++i){
      const int u_ = i*512 + tid;
      const int r = u_ >> 3, c = u_ & 7;
      gload_lds16(kt + (size_t)r*DK + ((c ^ (r&7))*8), dst + (i*512 + w*64)*8);
    }
  };
  auto p1buf = [&](int i){ return SM + (size_t)(i % 3) * 8192; };

  stage128(p1buf(0), 0);
  stage128(p1buf(1), 1);
  BARRIER_VM(2);                      // stage(0) complete everywhere; stage(1) in flight
  float l_part[4] = {};
  for (int t = 0; t < S/128; ++t){
    if (t + 2 < S/128) stage128(p1buf(t + 2), t + 2);   // overwrites buf[(t-1)%3], reads done
    const u16* cur = p1buf(t);
    #pragma unroll
    for (int sub = 0; sub < 2; ++sub){
      f32x4 s[4] = {};
      qk(cur + sub*4096, s);
      #pragma unroll
      for (int r = 0; r < 4; ++r)
        l_part[r] += exp2f(s[0][r]) + exp2f(s[1][r]) + exp2f(s[2][r]) + exp2f(s[3][r]);
    }
    if (t < S/128 - 1){
      if (t < S/128 - 2) { BARRIER_VM(2); }   // stage(t+1) done; stage(t+2) in flight
      else               { BARRIER_VM(0); }   // tail: only stage(t+1) outstanding
    }
  }
  float inv_l[4];
  #pragma unroll
  for (int r = 0; r < 4; ++r){
    float v = l_part[r];
    v += __shfl_xor(v, 1, 64);
    v += __shfl_xor(v, 2, 64);
    v += __shfl_xor(v, 4, 64);
    v += __shfl_xor(v, 8, 64);
    inv_l[r] = 1.0f / v;
  }
  BARRIER_VM(0);                      // all waves done reading p1buf(15) == SM[0..] before pass-2 staging

  // ---- pass 2: K+V 64-row tiles, nt stores ----
  const int sr = tid >> 3, sc = tid & 7;
  auto stageK = [&](int buf, int t){
    gload_lds16(Kb + (size_t)t*64*DK + (size_t)sr*DK + ((sc ^ (sr&7))*8),
                SM + buf*8192 + w*512);
  };
  auto stageV = [&](int buf, int t){
    gload_lds16(Vb + (size_t)sr*S + t*64 + ((sc ^ (sr&7))*8),
                SM + buf*8192 + 4096 + w*512);
  };

  stageK(0, 0); stageV(0, 0);
  BARRIER_VM(0);
  f32x4 o[4] = {};
  for (int t = 0; t < S/64; ++t){
    const int buf = t & 1;
    if (t + 1 < S/64){ stageK(buf ^ 1, t + 1); stageV(buf ^ 1, t + 1); }
    f32x4 s[4] = {};
    qk(SM + buf*8192, s);

    #pragma unroll
    for (int half = 0; half < 2; ++half){
      // normalized p (f32) into per-wave tile, chunk-XOR swizzled, pitch 40
      #pragma unroll
      for (int k2 = 0; k2 < 2; ++k2){
        const int kf = half*2 + k2;
        #pragma unroll
        for (int r = 0; r < 4; ++r){
          const int row = hi*4 + r;
          const int col = k2*16 + lo;
          Pf[w*640 + row*40 + ((((col>>2) ^ (row&7)) << 2) | (col & 3))] =
              exp2f(s[kf][r]) * inv_l[r];
        }
      }
      // coalesced NONTEMPORAL attn store: full 128B lines, L2-bypassing
      #pragma unroll
      for (int j = 0; j < 2; ++j){
        const int row = j*8 + (lane >> 3);
        const int cb  = (lane & 7) * 4;
        f32x4 vv = *reinterpret_cast<const f32x4*>(
            &Pf[w*640 + row*40 + ((((cb>>2) ^ (row&7)) << 2))]);
        __builtin_nontemporal_store(vv, reinterpret_cast<f32x4*>(
            &attn_b[(size_t)(q0 + row)*S + t*64 + half*32 + cb]));
      }
      // PV A-fragment from Pf
      {
        const int row = lo;
        const f32x4 pa = *reinterpret_cast<const f32x4*>(
            &Pf[w*640 + row*40 + (((2*hi) ^ (row&7)) << 2)]);
        const f32x4 pb = *reinterpret_cast<const f32x4*>(
            &Pf[w*640 + row*40 + (((2*hi + 1) ^ (row&7)) << 2)]);
        union { bf16x8 v; __hip_bfloat162 h[4]; } u_;
        u_.h[0] = __float22bfloat162_rn(float2{pa[0], pa[1]});
        u_.h[1] = __float22bfloat162_rn(float2{pa[2], pa[3]});
        u_.h[2] = __float22bfloat162_rn(float2{pb[0], pb[1]});
        u_.h[3] = __float22bfloat162_rn(float2{pb[2], pb[3]});
        bf16x8 bv[4];
        #pragma unroll
        for (int df = 0; df < 4; ++df){
          const int vrow = df*16 + lo;
          bv[df] = *reinterpret_cast<const bf16x8*>(
              &SM[buf*8192 + 4096 + vrow*64 + (((half*4 + hi) ^ (vrow&7))*8)]);
        }
        #pragma unroll
        for (int df = 0; df < 4; ++df)
          o[df] = __builtin_amdgcn_mfma_f32_16x16x32_bf16(u_.v, bv[df], o[df], 0, 0, 0);
      }
    }

    if (t + 1 < S/64){
      // 2 staging loads (oldest) done; 4 attn stores may stay in flight
      BARRIER_VM(4);
    }
  }

  // ctx epilogue via per-wave LDS: [b][s][h*64 + d] bf16, 16B/lane stores
  {
    u16* Pw = (u16*)(Pf + (size_t)w * 640);   // own wave's region (free now)
    #pragma unroll
    for (int df = 0; df < 4; ++df)
      #pragma unroll
      for (int r = 0; r < 4; ++r)
        Pw[(hi*4 + r)*64 + df*16 + lo] = f2bf(o[df][r]);
    const int b = bh >> 4, h = bh & 15;
    #pragma unroll
    for (int i = 0; i < 2; ++i){
      const int c = i*64 + lane;              // 128 chunks of 8 u16
      const int row = c >> 3, d0 = (c & 7) * 8;
      bf16x8 v = *reinterpret_cast<const bf16x8*>(&Pw[row*64 + d0]);
      *reinterpret_cast<bf16x8*>(
          &ctx[((size_t)b*S + q0 + row)*DMODEL + h*DK + d0]) = v;
    }
  }
}

// ---------- launch ----------
extern "C" void kernel_launch(void* const* d_in, const int* in_sizes, int n_in,
                              void* d_out, int out_size, void* d_ws, size_t ws_size,
                              hipStream_t stream)
{
  const float* q_in = (const float*)d_in[0];
  const float* k_in = (const float*)d_in[1];
  const float* v_in = (const float*)d_in[2];
  const float* wq   = (const float*)d_in[3];
  const float* wk   = (const float*)d_in[4];
  const float* wv   = (const float*)d_in[5];
  const float* wo   = (const float*)d_in[6];
  const float* bo   = (const float*)d_in[7];

  u16* ws = (u16*)d_ws;
  u16* X  = ws;                                          // Xq,Xk,Xv contiguous
  u16* W  = ws + (size_t)3*NROWS*DMODEL;                 // Wq,Wk,Wv,Wo contiguous
  u16* Wob= W  + (size_t)3*DMODEL*DMODEL;
  u16* Qh = W  + (size_t)4*DMODEL*DMODEL;
  u16* Kh = Qh + (size_t)NROWS*DMODEL;
  u16* Vt = Kh + (size_t)NROWS*DMODEL;
  u16* Ctx= Vt + (size_t)NROWS*DMODEL;                   // total 64 MiB

  cvt_all<<<dim3(4096, 7), 256, 0, stream>>>(q_in, k_in, v_in, wq, wk, wv, wo, ws);

  gemm_mha<false><<<dim3(32, 8, 3), 256, 0, stream>>>(X, W, Qh, Kh, Vt, nullptr, nullptr);

  float* out0 = (float*)d_out;
  float* attn = out0 + (size_t)NROWS * DMODEL;
  attn_fused<<<dim3(512), 512, 0, stream>>>(Qh, Kh, Vt, attn, Ctx);

  gemm_mha<true><<<dim3(32, 8), 256, 0, stream>>>(Ctx, Wob, nullptr, nullptr, nullptr, out0, bo);
}